// Round 1
// baseline (101493.341 us; speedup 1.0000x reference)
//
#include <hip/hip_runtime.h>

#define BB 32      // batch
#define TT 2048    // time steps
#define DD 128     // input dim (layer 1)
#define HH 256     // hidden
#define NBD 128    // blocks per direction
#define RPB 8      // gate rows per block = 4 gates x 2 j
#define NTH 512    // threads per block
#define KS 16      // k-slices (= NTH/32)

__device__ __forceinline__ float sigm(float x) { return 1.0f / (1.0f + __expf(-x)); }
__device__ __forceinline__ float tanh_f(float x) { return 1.0f - 2.0f / (__expf(2.0f * x) + 1.0f); }

// One bidirectional LSTM layer, persistent-grid, per-direction global barrier.
// Grid = 2*NBD blocks (block/128 = direction). Each block owns h-elements
// j in {2*bi, 2*bi+1} (i.e. 8 of the 1024 gate rows), holds its weight slice
// [W_ih | W_hh] in LDS for the whole scan, and exchanges h through a
// double-buffered global buffer with a release/acquire spin barrier.
template<int KIN, int LAYER>
__global__ __launch_bounds__(NTH)
void lstm_layer(const float* __restrict__ in_seq, long sb, long st,
                const float* __restrict__ wih_f, const float* __restrict__ whh_f,
                const float* __restrict__ bih_f, const float* __restrict__ bhh_f,
                const float* __restrict__ wih_r, const float* __restrict__ whh_r,
                const float* __restrict__ bih_r, const float* __restrict__ bhh_r,
                const float* __restrict__ hinit_f, const float* __restrict__ hinit_r,
                const float* __restrict__ cinit,   // layer2: [2dir][BB*HH]; layer1: unused
                float* __restrict__ hbuf,          // [2dir][2buf][BB*HH]
                float* __restrict__ cfin,          // layer1 out: [2dir][BB*HH]
                float* __restrict__ out1,          // layer1 out: [T][B][2H]
                float* __restrict__ acc,           // layer2 out: [T][B]
                const float* __restrict__ fcw,     // [2H]
                unsigned int* __restrict__ ctr)    // per-dir counter at ctr + dir*16
{
    constexpr int KZ  = KIN + HH;     // concatenated [x_t | h] width
    constexpr int KZP = KZ + 4;       // pad: rotates bank start by 4 per row
    constexpr int SLICE = KZ / KS;    // 24 (L1) / 48 (L2)
    constexpr int SL4 = SLICE / 4;

    const int blk = blockIdx.x;
    const int dir = blk >> 7;         // 0 fwd, 1 rev
    const int bi  = blk & 127;
    const int tid = threadIdx.x;

    __shared__ float W[RPB][KZ];
    __shared__ float z[BB][KZP];
    __shared__ float red[KS][RPB][BB];
    __shared__ float gates[RPB][BB];
    __shared__ float bias_s[RPB];

    const float* wih = dir ? wih_r : wih_f;
    const float* whh = dir ? whh_r : whh_f;
    const float* bih = dir ? bih_r : bih_f;
    const float* bhh = dir ? bhh_r : bhh_f;
    const float* hinit = dir ? hinit_r : hinit_f;

    // ---- one-time: load weight slice into LDS (reused for all 2048 steps) ----
    #pragma unroll
    for (int lr = 0; lr < RPB; ++lr) {
        const int row = (lr >> 1) * HH + bi * 2 + (lr & 1);   // gate-major rows i,f,g,o
        for (int k = tid; k < KIN; k += NTH) W[lr][k] = wih[(long)row * KIN + k];
        for (int k = tid; k < HH;  k += NTH) W[lr][KIN + k] = whh[row * HH + k];
    }
    if (tid < RPB) {
        const int row = (tid >> 1) * HH + bi * 2 + (tid & 1);
        bias_s[tid] = bih[row] + bhh[row];
    }

    float* hb0 = hbuf + (dir * 2 + 0) * (BB * HH);
    float* hb1 = hbuf + (dir * 2 + 1) * (BB * HH);

    const int b  = tid & 31;
    const int ks = tid >> 5;          // 0..15 (k-slice role)
    const int jp_a = tid >> 5;        // activation role (valid tid<64): 0/1

    float creg = 0.0f;
    if (LAYER == 2 && tid < 64) creg = cinit[(dir * BB + b) * HH + bi * 2 + jp_a];

    unsigned int* cnt = ctr + dir * 16;   // separate cache line per direction

    for (int s = 0; s < TT; ++s) {
        const int t = dir ? (TT - 1 - s) : s;
        const float* hsrc = (s == 0) ? hinit : ((s & 1) ? hb1 : hb0);
        float* hdst = ((s + 1) & 1) ? hb1 : hb0;

        // ---- stage z = [in_t | h_prev] into LDS (b-major, float4 copies) ----
        {
            constexpr int NF4 = (KIN / 4) * BB;
            const long tbase = (long)t * st;
            for (int q = tid; q < NF4; q += NTH) {
                const int bq = q / (KIN / 4);
                const int k4 = q % (KIN / 4);
                const float4 v = *(const float4*)(in_seq + bq * sb + tbase + k4 * 4);
                *(float4*)&z[bq][k4 * 4] = v;
            }
            constexpr int NH4 = (HH / 4) * BB;
            for (int q = tid; q < NH4; q += NTH) {
                const int bq = q >> 6;
                const int k4 = q & 63;
                const float4 v = *(const float4*)(hsrc + bq * HH + k4 * 4);
                *(float4*)&z[bq][KIN + k4 * 4] = v;
            }
        }
        __syncthreads();

        // ---- split-K partial dot products: thread (ks, b) does 8 rows ----
        {
            float a[RPB];
            #pragma unroll
            for (int r = 0; r < RPB; ++r) a[r] = 0.0f;
            const int k0 = ks * SLICE;
            #pragma unroll 2
            for (int k4 = 0; k4 < SL4; ++k4) {
                const int k = k0 + k4 * 4;
                const float4 zv = *(const float4*)&z[b][k];
                #pragma unroll
                for (int r = 0; r < RPB; ++r) {
                    const float4 wv = *(const float4*)&W[r][k];
                    a[r] = fmaf(wv.x, zv.x, a[r]);
                    a[r] = fmaf(wv.y, zv.y, a[r]);
                    a[r] = fmaf(wv.z, zv.z, a[r]);
                    a[r] = fmaf(wv.w, zv.w, a[r]);
                }
            }
            #pragma unroll
            for (int r = 0; r < RPB; ++r) red[ks][r][b] = a[r];
        }
        __syncthreads();

        // ---- reduce k-slices -> gate pre-activations ----
        if (tid < RPB * BB) {
            const int r = tid >> 5;
            float sg = bias_s[r];
            #pragma unroll
            for (int q = 0; q < KS; ++q) sg += red[q][r][b];
            gates[r][b] = sg;
        }
        __syncthreads();

        // ---- LSTM cell update + global writes (64 threads: 2 j x 32 b) ----
        if (tid < 64) {
            const int jg = bi * 2 + jp_a;
            const float gi = gates[0 + jp_a][b];
            const float gf = gates[2 + jp_a][b];
            const float gg = gates[4 + jp_a][b];
            const float go = gates[6 + jp_a][b];
            const float iv = sigm(gi), fv = sigm(gf);
            const float gv = tanh_f(gg), ov = sigm(go);
            creg = fv * creg + iv * gv;
            const float hv = ov * tanh_f(creg);
            hdst[b * HH + jg] = hv;
            if (LAYER == 1) {
                out1[((long)t * BB + b) * (2 * HH) + dir * HH + jg] = hv;
                if (s == TT - 1) cfin[(dir * BB + b) * HH + jg] = creg;
            } else {
                float val = hv * fcw[dir * HH + jg];
                val += __shfl_down(val, 32, 64);           // combine the two j's
                if (jp_a == 0) atomicAdd(&acc[t * BB + b], val);
            }
            __threadfence();   // agent-scope release of this thread's stores
        }

        // ---- per-direction global barrier (monotonic counter, all co-resident) ----
        __syncthreads();
        if (tid == 0) {
            __hip_atomic_fetch_add(cnt, 1u, __ATOMIC_RELEASE, __HIP_MEMORY_SCOPE_AGENT);
            const unsigned int target = (unsigned)(s + 1) * NBD;
            while (__hip_atomic_load(cnt, __ATOMIC_ACQUIRE, __HIP_MEMORY_SCOPE_AGENT) < target)
                __builtin_amdgcn_s_sleep(1);
        }
        __syncthreads();
    }
}

__global__ void finalize_k(const float* __restrict__ acc, const float* __restrict__ fcb,
                           float* __restrict__ out)
{
    const int i = blockIdx.x * blockDim.x + threadIdx.x;
    if (i < BB * TT) {
        const int b = i >> 11;       // /TT
        const int t = i & (TT - 1);
        out[i] = tanhf(acc[t * BB + b] + fcb[0]);
    }
}

extern "C" void kernel_launch(void* const* d_in, const int* in_sizes, int n_in,
                              void* d_out, int out_size, void* d_ws, size_t ws_size,
                              hipStream_t stream) {
    const float* x     = (const float*)d_in[0];
    const float* wih1f = (const float*)d_in[1];
    const float* whh1f = (const float*)d_in[2];
    const float* bih1f = (const float*)d_in[3];
    const float* bhh1f = (const float*)d_in[4];
    const float* wih1r = (const float*)d_in[5];
    const float* whh1r = (const float*)d_in[6];
    const float* bih1r = (const float*)d_in[7];
    const float* bhh1r = (const float*)d_in[8];
    const float* wih2f = (const float*)d_in[9];
    const float* whh2f = (const float*)d_in[10];
    const float* bih2f = (const float*)d_in[11];
    const float* bhh2f = (const float*)d_in[12];
    const float* wih2r = (const float*)d_in[13];
    const float* whh2r = (const float*)d_in[14];
    const float* bih2r = (const float*)d_in[15];
    const float* bhh2r = (const float*)d_in[16];
    const float* fcw   = (const float*)d_in[17];
    const float* fcb   = (const float*)d_in[18];

    char* ws = (char*)d_ws;
    size_t off = 0;
    unsigned int* ctr = (unsigned int*)(ws + off); off += 512;
    float* acc   = (float*)(ws + off); off += (size_t)TT * BB * 4;        // 256 KB
    float* hbuf1 = (float*)(ws + off); off += (size_t)4 * BB * HH * 4;    // 128 KB
    float* hbuf2 = (float*)(ws + off); off += (size_t)4 * BB * HH * 4;    // 128 KB
    const size_t clear_bytes = off;                                        // zeroed every launch
    float* cfin1 = (float*)(ws + off); off += (size_t)2 * BB * HH * 4;    // 64 KB
    float* out1  = (float*)(ws + off); off += (size_t)TT * BB * 2 * HH * 4; // 128 MB

    // counters, acc (atomic target), hbuf1 (h0 = 0) must be zero each launch
    hipMemsetAsync(d_ws, 0, clear_bytes, stream);

    // layer 1: input = x (B,T,D) -> addr b*(T*D) + t*D + k
    lstm_layer<DD, 1><<<2 * NBD, NTH, 0, stream>>>(
        x, (long)TT * DD, (long)DD,
        wih1f, whh1f, bih1f, bhh1f, wih1r, whh1r, bih1r, bhh1r,
        hbuf1 + 0, hbuf1 + 2 * BB * HH,      // h0 = zeroed buf0 of each dir
        nullptr,
        hbuf1, cfin1, out1, nullptr, nullptr, ctr);

    // layer 2: input = out1 (T,B,2H) -> addr b*(2H) + t*(B*2H) + k
    // initial (h,c) = layer-1 finals: h final lands in hbuf1 dir-buf0, c in cfin1
    lstm_layer<2 * HH, 2><<<2 * NBD, NTH, 0, stream>>>(
        out1, (long)2 * HH, (long)BB * 2 * HH,
        wih2f, whh2f, bih2f, bhh2f, wih2r, whh2r, bih2r, bhh2r,
        hbuf1 + 0, hbuf1 + 2 * BB * HH,
        cfin1,
        hbuf2, nullptr, nullptr, acc, fcw, ctr + 64);

    finalize_k<<<(BB * TT + 255) / 256, 256, 0, stream>>>(acc, fcb, (float*)d_out);
}

// Round 2
// 69411.566 us; speedup vs baseline: 1.4622x; 1.4622x over previous
//
#include <hip/hip_runtime.h>

#define BB 32      // batch
#define TT 2048    // time steps
#define DD 128     // input dim (layer 1)
#define HH 256     // hidden
#define NTH 256    // threads per block
#define NRANK 32   // blocks (ranks) per group
#define NGRP 8     // groups = 2 dirs x 4 batch-quads; group = blockIdx & 7 -> XCD

__device__ __forceinline__ float sigm(float x)  { return 1.0f / (1.0f + __expf(-x)); }
__device__ __forceinline__ float tanh_f(float x){ return 1.0f - 2.0f / (__expf(2.0f * x) + 1.0f); }

// Persistent scan. 256 blocks = 8 groups x 32 ranks, 1 block/CU (LDS-bound).
// group g: dir = g&1, batch-quad = g>>1 (8 batches). rank owns j in
// [rank*8, rank*8+8) => 32 gate rows, weights in LDS for the whole scan.
// x is folded into the per-step dot (K = KIN + HH), no precomputed xw.
// Barrier: per-rank 64B flag slot (release store), wave-0 polls all 32 slots
// (acquire loads) -- zero atomic-RMW contention.
template<int KIN, int LAYER>
__global__ __launch_bounds__(NTH, 1)
void lstm_scan(const float* __restrict__ in_seq, long sb, long st,
               const float* __restrict__ wih_f, const float* __restrict__ whh_f,
               const float* __restrict__ bih_f, const float* __restrict__ bhh_f,
               const float* __restrict__ wih_r, const float* __restrict__ whh_r,
               const float* __restrict__ bih_r, const float* __restrict__ bhh_r,
               float* __restrict__ hseed,      // [NGRP][8][HH]
               float* __restrict__ cseed,      // [NGRP][8][HH]
               float* __restrict__ hbuf,       // [NGRP][2][8][HH]
               float* __restrict__ out1,       // [TT][BB][2H] (layer1 out)
               float* __restrict__ acc,        // [TT][BB]     (layer2 out)
               const float* __restrict__ fcw,  // [2H]
               unsigned int* __restrict__ flags) // [NGRP][NRANK][16 uints]
{
    constexpr int KZ  = KIN + HH;   // 384 (L1) / 768 (L2)
    constexpr int KZP = KZ + 4;     // pad -> bank rotation of 4 per row
    constexpr int C4  = KIN / 4;    // pow2 (32 / 128)

    const int blk  = blockIdx.x;
    const int g    = blk & 7;
    const int rank = blk >> 3;
    const int dir  = g & 1;
    const int bq   = g >> 1;
    const int tid  = threadIdx.x;

    __shared__ __align__(16) float W[32][KZP];     // 32 rows = 4 gates x 8 j
    __shared__ __align__(16) float z[8][KZP];      // [b_local][x|h]
    __shared__ float gates_s[4][8][9];
    __shared__ float bias_s[32];

    const float* wih = dir ? wih_r : wih_f;
    const float* whh = dir ? whh_r : whh_f;
    const float* bih = dir ? bih_r : bih_f;
    const float* bhh = dir ? bhh_r : bhh_f;

    // ---- one-time: weight slice -> LDS (reused 2048 steps) ----
    {
        constexpr int NC = 32 * (KZ / 4);
        for (int q = tid; q < NC; q += NTH) {
            const int r = q / (KZ / 4);
            const int k = (q - r * (KZ / 4)) * 4;
            const int row = (r >> 3) * HH + rank * 8 + (r & 7);
            float4 v;
            if (k < KIN) v = *(const float4*)(wih + (long)row * KIN + k);
            else         v = *(const float4*)(whh + (long)row * HH + (k - KIN));
            *(float4*)&W[r][k] = v;
        }
        if (tid < 32) {
            const int row = (tid >> 3) * HH + rank * 8 + (tid & 7);
            bias_s[tid] = bih[row] + bhh[row];
        }
    }

    float* hb      = hbuf  + g * (2 * 8 * HH);
    float* hs_seed = hseed + g * (8 * HH);
    float* cs_seed = cseed + g * (8 * HH);
    unsigned int* flags_g = flags + g * (NRANK * 16);
    unsigned int* myslot  = flags_g + rank * 16;

    // dot roles: wave = one gate; lanes = 8 j x 8 b
    const int gate = tid >> 6;
    const int jjc  = (tid >> 3) & 7;
    const int blc  = tid & 7;
    const int wr   = gate * 8 + jjc;

    // update roles (tid < 64): (jj2, bl2)
    const int jj2   = tid >> 3;
    const int bl2   = tid & 7;
    const int jglob = rank * 8 + jj2;

    float creg = 0.0f;
    if (tid < 64) creg = cs_seed[bl2 * HH + jglob];   // zeros for layer 1

    __syncthreads();

    for (int s = 0; s < TT; ++s) {
        const int t = dir ? (TT - 1 - s) : s;
        const float* hsrc = (s == 0) ? hs_seed : (hb + ((s + 1) & 1) * (8 * HH));
        float* hdst = hb + (s & 1) * (8 * HH);

        // ---- stage z = [x_t | h_prev] (float4, conflict-free) ----
        {
            const long tb = (long)t * st;
            for (int q = tid; q < 8 * C4; q += NTH) {
                const int bl = q / C4;
                const int k4 = q & (C4 - 1);
                const float4 v = *(const float4*)(in_seq + (long)(bq * 8 + bl) * sb + tb + k4 * 4);
                *(float4*)&z[bl][k4 * 4] = v;
            }
            for (int q = tid; q < 8 * 64; q += NTH) {
                const int bl = q >> 6;
                const int k4 = q & 63;
                const float4 v = *(const float4*)(hsrc + bl * HH + k4 * 4);
                *(float4*)&z[bl][KIN + k4 * 4] = v;
            }
        }
        __syncthreads();

        // ---- full-K dot: one gate row per thread ----
        {
            float a = 0.0f;
            #pragma unroll 8
            for (int k4 = 0; k4 < KZ / 4; ++k4) {
                const float4 zv = *(const float4*)&z[blc][k4 * 4];
                const float4 wv = *(const float4*)&W[wr][k4 * 4];
                a = fmaf(wv.x, zv.x, a);
                a = fmaf(wv.y, zv.y, a);
                a = fmaf(wv.z, zv.z, a);
                a = fmaf(wv.w, zv.w, a);
            }
            gates_s[gate][jjc][blc] = a + bias_s[wr];
        }
        __syncthreads();

        const unsigned int tgt = (unsigned int)(s + 1);

        // ---- cell update + outputs (wave 0: 8 j x 8 b) ----
        if (tid < 64) {
            const float gi = gates_s[0][jj2][bl2];
            const float gf = gates_s[1][jj2][bl2];
            const float gg = gates_s[2][jj2][bl2];
            const float go = gates_s[3][jj2][bl2];
            creg = sigm(gf) * creg + sigm(gi) * tanh_f(gg);
            const float hv = sigm(go) * tanh_f(creg);
            hdst[bl2 * HH + jglob] = hv;
            if (LAYER == 1) {
                out1[(long)t * (BB * 2 * HH) + (bq * 8 + bl2) * (2 * HH) + dir * HH + jglob] = hv;
                if (s == TT - 1) {
                    hs_seed[bl2 * HH + jglob] = hv;
                    cs_seed[bl2 * HH + jglob] = creg;
                }
            } else {
                float val = hv * fcw[dir * HH + jglob];
                val += __shfl_down(val, 32, 64);
                val += __shfl_down(val, 16, 64);
                val += __shfl_down(val, 8, 64);
                if (jj2 == 0) atomicAdd(&acc[t * BB + bq * 8 + bl2], val);
            }
            __threadfence();   // drain h/out stores before flag
        }
        __syncthreads();

        // ---- flag barrier: own-slot release store, poll 32 slots ----
        if (tid == 0)
            __hip_atomic_store(myslot, tgt, __ATOMIC_RELEASE, __HIP_MEMORY_SCOPE_AGENT);
        if (tid < 64) {
            const unsigned int* slot = flags_g + (tid & 31) * 16;
            while (true) {
                const unsigned int v = (tid < 32)
                    ? __hip_atomic_load(slot, __ATOMIC_ACQUIRE, __HIP_MEMORY_SCOPE_AGENT)
                    : tgt;
                if (__all((int)(v >= tgt))) break;
                __builtin_amdgcn_s_sleep(1);
            }
        }
        __syncthreads();
    }
}

__global__ void finalize_k(const float* __restrict__ acc, const float* __restrict__ fcb,
                           float* __restrict__ out)
{
    const int i = blockIdx.x * blockDim.x + threadIdx.x;
    if (i < BB * TT) {
        const int b = i >> 11;
        const int t = i & (TT - 1);
        out[i] = tanhf(acc[t * BB + b] + fcb[0]);
    }
}

extern "C" void kernel_launch(void* const* d_in, const int* in_sizes, int n_in,
                              void* d_out, int out_size, void* d_ws, size_t ws_size,
                              hipStream_t stream) {
    const float* x     = (const float*)d_in[0];
    const float* wih1f = (const float*)d_in[1];
    const float* whh1f = (const float*)d_in[2];
    const float* bih1f = (const float*)d_in[3];
    const float* bhh1f = (const float*)d_in[4];
    const float* wih1r = (const float*)d_in[5];
    const float* whh1r = (const float*)d_in[6];
    const float* bih1r = (const float*)d_in[7];
    const float* bhh1r = (const float*)d_in[8];
    const float* wih2f = (const float*)d_in[9];
    const float* whh2f = (const float*)d_in[10];
    const float* bih2f = (const float*)d_in[11];
    const float* bhh2f = (const float*)d_in[12];
    const float* wih2r = (const float*)d_in[13];
    const float* whh2r = (const float*)d_in[14];
    const float* bih2r = (const float*)d_in[15];
    const float* bhh2r = (const float*)d_in[16];
    const float* fcw   = (const float*)d_in[17];
    const float* fcb   = (const float*)d_in[18];

    char* ws = (char*)d_ws;
    size_t off = 0;
    unsigned int* flags = (unsigned int*)(ws + off); off += (size_t)2 * NGRP * NRANK * 16 * 4; // 32 KB
    float* acc   = (float*)(ws + off); off += (size_t)TT * BB * 4;                 // 256 KB
    float* hbuf  = (float*)(ws + off); off += (size_t)NGRP * 2 * 8 * HH * 4;       // 128 KB
    float* hseed = (float*)(ws + off); off += (size_t)NGRP * 8 * HH * 4;           // 64 KB
    float* cseed = (float*)(ws + off); off += (size_t)NGRP * 8 * HH * 4;           // 64 KB
    const size_t clear_bytes = off;
    float* out1  = (float*)(ws + off); off += (size_t)TT * BB * 2 * HH * 4;        // 128 MB

    // flags, acc (atomic target), seeds (h0=c0=0 for layer 1) zeroed each launch
    hipMemsetAsync(d_ws, 0, clear_bytes, stream);

    // layer 1: x (B,T,D): addr = b*(T*D) + t*D + k
    lstm_scan<DD, 1><<<NGRP * NRANK, NTH, 0, stream>>>(
        x, (long)TT * DD, (long)DD,
        wih1f, whh1f, bih1f, bhh1f, wih1r, whh1r, bih1r, bhh1r,
        hseed, cseed, hbuf, out1, nullptr, nullptr, flags);

    // layer 2: out1 (T,B,2H): addr = b*(2H) + t*(B*2H) + k; seeds = layer-1 finals
    lstm_scan<2 * HH, 2><<<NGRP * NRANK, NTH, 0, stream>>>(
        out1, (long)(2 * HH), (long)(BB * 2 * HH),
        wih2f, whh2f, bih2f, bhh2f, wih2r, whh2r, bih2r, bhh2r,
        hseed, cseed, hbuf, nullptr, acc, fcw, flags + NGRP * NRANK * 16);

    finalize_k<<<(BB * TT + 255) / 256, 256, 0, stream>>>(acc, fcb, (float*)d_out);
}

// Round 3
// 20284.596 us; speedup vs baseline: 5.0035x; 3.4219x over previous
//
#include <hip/hip_runtime.h>

#define BB 32      // batch
#define TT 2048    // time steps
#define DD 128     // input dim (layer 1)
#define HH 256     // hidden
#define NTH 256    // threads per block
#define NRANK 32   // blocks (ranks) per group
#define NGRP 8     // groups = 2 dirs x 4 batch-quads; group = blockIdx & 7

typedef float f32x4 __attribute__((ext_vector_type(4)));

__device__ __forceinline__ float sigm(float x)  { return 1.0f / (1.0f + __expf(-x)); }
__device__ __forceinline__ float tanh_f(float x){ return 1.0f - 2.0f / (__expf(2.0f * x) + 1.0f); }

// Persistent bidirectional scan; 256 blocks = 8 groups x 32 ranks, 1 block/CU.
// Cross-rank h exchange via Infinity-Cache write-through (sc0 sc1) stores +
// bypass loads; per-rank monotonic flag slots with RELAXED agent atomics.
// NO release/acquire C++ atomics in the loop => no buffer_wbl2 / buffer_inv.
template<int KIN, int LAYER>
__global__ __launch_bounds__(NTH, 1)
void lstm_scan(const float* __restrict__ in_seq, long sb, long st,
               const float* __restrict__ wih_f, const float* __restrict__ whh_f,
               const float* __restrict__ bih_f, const float* __restrict__ bhh_f,
               const float* __restrict__ wih_r, const float* __restrict__ whh_r,
               const float* __restrict__ bih_r, const float* __restrict__ bhh_r,
               float* __restrict__ hseed,        // [NGRP][8][HH]
               float* __restrict__ cseed,        // [NGRP][8][HH]
               float* __restrict__ hbuf,         // [NGRP][2][8][HH]
               float* __restrict__ out1,         // [TT][BB][2H]
               float* __restrict__ acc,          // [TT][BB]
               const float* __restrict__ fcw,    // [2H]
               unsigned int* __restrict__ flags, // [NGRP][NRANK][16]
               int never)
{
    constexpr int KZ   = KIN + HH;
    constexpr int KZP  = KZ + 4;      // W row stride (772 / 388), %32 == 4
    constexpr int KINP = KIN + 4;     // zx row stride (516 / 132), %32 == 4
    constexpr int HHP  = HH + 4;      // zh row stride (260),       %32 == 4
    constexpr int C4   = KIN / 4;
    constexpr int NPX  = (8 * C4) / NTH;     // x-prefetch f4 per thread (1 / 4)
    constexpr int PADN = (LAYER == 1) ? 5120 : 4;  // keep L1 LDS > 80KB: 1 block/CU

    const int blk  = blockIdx.x;
    const int g    = blk & 7;
    const int rank = blk >> 3;
    const int dir  = g & 1;
    const int bq   = g >> 1;
    const int tid  = threadIdx.x;

    __shared__ __align__(16) float W[32][KZP];
    __shared__ __align__(16) float zx[8][KINP];
    __shared__ __align__(16) float zh[8][HHP];
    __shared__ float gates_s[4][8][9];
    __shared__ float bias_s[32];
    __shared__ float padlds[PADN];
    if (never) padlds[never & (PADN - 1)] = 1.0f;   // keep padlds alive

    const float* wih = dir ? wih_r : wih_f;
    const float* whh = dir ? whh_r : whh_f;
    const float* bih = dir ? bih_r : bih_f;
    const float* bhh = dir ? bhh_r : bhh_f;

    // ---- one-time: weight slice -> LDS ----
    {
        constexpr int NC = 32 * (KZ / 4);
        for (int q = tid; q < NC; q += NTH) {
            const int r = q / (KZ / 4);
            const int k = (q - r * (KZ / 4)) * 4;
            const int row = (r >> 3) * HH + rank * 8 + (r & 7);
            f32x4 v;
            if (k < KIN) v = *(const f32x4*)(wih + (long)row * KIN + k);
            else         v = *(const f32x4*)(whh + (long)row * HH + (k - KIN));
            *(f32x4*)&W[r][k] = v;
        }
        if (tid < 32) {
            const int row = (tid >> 3) * HH + rank * 8 + (tid & 7);
            bias_s[tid] = bih[row] + bhh[row];
        }
    }

    float* hb      = hbuf  + g * (2 * 8 * HH);
    float* hs_seed = hseed + g * (8 * HH);
    float* cs_seed = cseed + g * (8 * HH);
    unsigned int* flags_g = flags + g * (NRANK * 16);
    unsigned int* myslot  = flags_g + rank * 16;

    // dot roles: wave = gate, lanes = 8 j x 8 b
    const int gate = tid >> 6;
    const int jjc  = (tid >> 3) & 7;
    const int blc  = tid & 7;
    const int wr   = gate * 8 + jjc;

    // update roles (tid < 64)
    const int jj2   = tid >> 3;
    const int bl2   = tid & 7;
    const int jglob = rank * 8 + jj2;

    float creg = 0.0f, fcv = 0.0f;
    if (tid < 64) {
        creg = cs_seed[bl2 * HH + jglob];           // zeros for layer 1
        if (LAYER == 2) fcv = fcw[dir * HH + jglob];
    }

    // ---- prolog: stage x-part of z for s = 0 ----
    {
        const int t0 = dir ? (TT - 1) : 0;
        const long tb = (long)t0 * st;
        for (int q = tid; q < 8 * C4; q += NTH) {
            const int bl = q / C4;
            const int k4 = q - bl * C4;
            *(f32x4*)&zx[bl][k4 * 4] =
                *(const f32x4*)(in_seq + (long)(bq * 8 + bl) * sb + tb + k4 * 4);
        }
    }
    __syncthreads();

    for (int s = 0; s < TT; ++s) {
        const int t = dir ? (TT - 1 - s) : s;

        // ---- P0: prefetch x slice for step s+1 into registers ----
        f32x4 px[NPX];
        if (s + 1 < TT) {
            const long tb = (long)(dir ? (t - 1) : (t + 1)) * st;
            #pragma unroll
            for (int i = 0; i < NPX; ++i) {
                const int q  = tid + i * NTH;
                const int bl = q / C4;
                const int k4 = q - bl * C4;
                px[i] = *(const f32x4*)(in_seq + (long)(bq * 8 + bl) * sb + tb + k4 * 4);
            }
        }

        // ---- P1: x-part of the dot (no h needed) ----
        float a = bias_s[wr];
        #pragma unroll 4
        for (int k4 = 0; k4 < C4; ++k4) {
            const f32x4 zv = *(const f32x4*)&zx[blc][k4 * 4];
            const f32x4 wv = *(const f32x4*)&W[wr][k4 * 4];
            a = fmaf(wv.x, zv.x, a);
            a = fmaf(wv.y, zv.y, a);
            a = fmaf(wv.z, zv.z, a);
            a = fmaf(wv.w, zv.w, a);
        }

        // ---- P2: poll flags (relaxed, no cache maintenance) ----
        if (s > 0 && tid < 64) {
            const unsigned int tgt = (unsigned int)s;
            const unsigned int* slot = flags_g + (tid & 31) * 16;
            while (true) {
                const unsigned int v = (tid < 32)
                    ? __hip_atomic_load(slot, __ATOMIC_RELAXED, __HIP_MEMORY_SCOPE_AGENT)
                    : tgt;
                if (__all((int)(v >= tgt))) break;
                __builtin_amdgcn_s_sleep(2);
            }
        }
        __syncthreads();

        // ---- P3: stage h(s) -> zh via coherence-point loads ----
        {
            const float* hsrc = (s == 0) ? hs_seed : (hb + ((s + 1) & 1) * (8 * HH));
            const int q0 = tid, q1 = tid + NTH;
            const float* p0 = hsrc + (q0 >> 6) * HH + (q0 & 63) * 4;
            const float* p1 = hsrc + (q1 >> 6) * HH + (q1 & 63) * 4;
            f32x4 h0, h1;
            asm volatile(
                "global_load_dwordx4 %0, %2, off sc0 sc1\n\t"
                "global_load_dwordx4 %1, %3, off sc0 sc1\n\t"
                "s_waitcnt vmcnt(0)"
                : "=&v"(h0), "=&v"(h1) : "v"(p0), "v"(p1) : "memory");
            *(f32x4*)&zh[q0 >> 6][(q0 & 63) * 4] = h0;
            *(f32x4*)&zh[q1 >> 6][(q1 & 63) * 4] = h1;
        }
        __syncthreads();

        // ---- P4: h-part of the dot ----
        #pragma unroll 4
        for (int kk = 0; kk < HH / 4; ++kk) {
            const f32x4 zv = *(const f32x4*)&zh[blc][kk * 4];
            const f32x4 wv = *(const f32x4*)&W[wr][KIN + kk * 4];
            a = fmaf(wv.x, zv.x, a);
            a = fmaf(wv.y, zv.y, a);
            a = fmaf(wv.z, zv.z, a);
            a = fmaf(wv.w, zv.w, a);
        }
        gates_s[gate][jjc][blc] = a;
        __syncthreads();

        // ---- P5: cell update, coherent h store, flag; stage px -> zx ----
        if (tid < 64) {
            const float gi = gates_s[0][jj2][bl2];
            const float gf = gates_s[1][jj2][bl2];
            const float gg = gates_s[2][jj2][bl2];
            const float go = gates_s[3][jj2][bl2];
            creg = sigm(gf) * creg + sigm(gi) * tanh_f(gg);
            const float hv = sigm(go) * tanh_f(creg);
            if (s + 1 < TT) {
                float* hdst = hb + (s & 1) * (8 * HH);
                float* hp = hdst + bl2 * HH + jglob;
                asm volatile("global_store_dword %0, %1, off sc0 sc1"
                             :: "v"(hp), "v"(hv) : "memory");
                if (tid == 0) {
                    asm volatile("s_waitcnt vmcnt(0)" ::: "memory");
                    __hip_atomic_store(myslot, (unsigned int)(s + 1),
                                       __ATOMIC_RELAXED, __HIP_MEMORY_SCOPE_AGENT);
                }
            }
            if (LAYER == 1) {
                out1[(long)t * (BB * 2 * HH) + (bq * 8 + bl2) * (2 * HH) + dir * HH + jglob] = hv;
                if (s == TT - 1) {
                    hs_seed[bl2 * HH + jglob] = hv;
                    cs_seed[bl2 * HH + jglob] = creg;
                }
            } else {
                float val = hv * fcv;
                val += __shfl_down(val, 32, 64);
                val += __shfl_down(val, 16, 64);
                val += __shfl_down(val, 8, 64);
                if (jj2 == 0) atomicAdd(&acc[t * BB + bq * 8 + bl2], val);
            }
        }
        if (s + 1 < TT) {
            #pragma unroll
            for (int i = 0; i < NPX; ++i) {
                const int q  = tid + i * NTH;
                const int bl = q / C4;
                const int k4 = q - bl * C4;
                *(f32x4*)&zx[bl][k4 * 4] = px[i];
            }
        }
        __syncthreads();
    }
}

__global__ void finalize_k(const float* __restrict__ acc, const float* __restrict__ fcb,
                           float* __restrict__ out)
{
    const int i = blockIdx.x * blockDim.x + threadIdx.x;
    if (i < BB * TT) {
        const int b = i >> 11;
        const int t = i & (TT - 1);
        out[i] = tanhf(acc[t * BB + b] + fcb[0]);
    }
}

extern "C" void kernel_launch(void* const* d_in, const int* in_sizes, int n_in,
                              void* d_out, int out_size, void* d_ws, size_t ws_size,
                              hipStream_t stream) {
    const float* x     = (const float*)d_in[0];
    const float* wih1f = (const float*)d_in[1];
    const float* whh1f = (const float*)d_in[2];
    const float* bih1f = (const float*)d_in[3];
    const float* bhh1f = (const float*)d_in[4];
    const float* wih1r = (const float*)d_in[5];
    const float* whh1r = (const float*)d_in[6];
    const float* bih1r = (const float*)d_in[7];
    const float* bhh1r = (const float*)d_in[8];
    const float* wih2f = (const float*)d_in[9];
    const float* whh2f = (const float*)d_in[10];
    const float* bih2f = (const float*)d_in[11];
    const float* bhh2f = (const float*)d_in[12];
    const float* wih2r = (const float*)d_in[13];
    const float* whh2r = (const float*)d_in[14];
    const float* bih2r = (const float*)d_in[15];
    const float* bhh2r = (const float*)d_in[16];
    const float* fcw   = (const float*)d_in[17];
    const float* fcb   = (const float*)d_in[18];

    char* ws = (char*)d_ws;
    size_t off = 0;
    unsigned int* flags = (unsigned int*)(ws + off); off += (size_t)2 * NGRP * NRANK * 16 * 4;
    float* acc   = (float*)(ws + off); off += (size_t)TT * BB * 4;
    float* hbuf  = (float*)(ws + off); off += (size_t)NGRP * 2 * 8 * HH * 4;
    float* hseed = (float*)(ws + off); off += (size_t)NGRP * 8 * HH * 4;
    float* cseed = (float*)(ws + off); off += (size_t)NGRP * 8 * HH * 4;
    const size_t clear_bytes = off;
    float* out1  = (float*)(ws + off); off += (size_t)TT * BB * 2 * HH * 4;

    hipMemsetAsync(d_ws, 0, clear_bytes, stream);

    // layer 1: x (B,T,D)
    lstm_scan<DD, 1><<<NGRP * NRANK, NTH, 0, stream>>>(
        x, (long)TT * DD, (long)DD,
        wih1f, whh1f, bih1f, bhh1f, wih1r, whh1r, bih1r, bhh1r,
        hseed, cseed, hbuf, out1, nullptr, nullptr, flags, 0);

    // layer 2: out1 (T,B,2H); seeds = layer-1 finals
    lstm_scan<2 * HH, 2><<<NGRP * NRANK, NTH, 0, stream>>>(
        out1, (long)(2 * HH), (long)(BB * 2 * HH),
        wih2f, whh2f, bih2f, bhh2f, wih2r, whh2r, bih2r, bhh2r,
        hseed, cseed, hbuf, nullptr, acc, fcw, flags + NGRP * NRANK * 16, 0);

    finalize_k<<<(BB * TT + 255) / 256, 256, 0, stream>>>(acc, fcb, (float*)d_out);
}

// Round 4
// 13386.488 us; speedup vs baseline: 7.5818x; 1.5153x over previous
//
#include <hip/hip_runtime.h>

#define BB 32      // batch
#define TT 2048    // time steps
#define DD 128     // input dim (layer 1)
#define HH 256     // hidden
#define NTH 256    // threads per block
#define NRANK 32   // blocks (ranks) per group
#define NGRP 8     // groups = 2 dirs x 4 batch-quads
#define HASHK 2654435761u

typedef float f32x4 __attribute__((ext_vector_type(4)));
typedef unsigned int u32;
typedef u32 u32x2 __attribute__((ext_vector_type(2)));
typedef u32 u32x4 __attribute__((ext_vector_type(4)));

__device__ __forceinline__ float sigm(float x)  { return 1.0f / (1.0f + __expf(-x)); }
__device__ __forceinline__ float tanh_f(float x){ return 1.0f - 2.0f / (__expf(2.0f * x) + 1.0f); }

// Persistent bidirectional scan; 256 blocks = 8 groups x 32 ranks, 1 block/CU.
// h exchange: fused (h, tag) 8-byte packets via IC write-through (sc0 sc1);
// tag = step + h_bits*HASHK (bijective in h_bits -> torn reads detected).
// Consumers spin-load packets directly: no flags, no producer vmcnt wait.
// Dot is register-blocked 4 gates x 2 b: LDS/FMA ratio 0.19 (was 0.5).
template<int KIN, int LAYER>
__global__ __launch_bounds__(NTH, 1)
void lstm_scan(const float* __restrict__ in_seq, long sb, long st,
               const float* __restrict__ wih_f, const float* __restrict__ whh_f,
               const float* __restrict__ bih_f, const float* __restrict__ bhh_f,
               const float* __restrict__ wih_r, const float* __restrict__ whh_r,
               const float* __restrict__ bih_r, const float* __restrict__ bhh_r,
               float* __restrict__ hseed,      // [NGRP][8][HH] (L1 writes, L2 reads)
               float* __restrict__ cseed,      // [NGRP][8][HH]
               u32* __restrict__ hbt,          // [NGRP][2par][8b][256j][2] (h,tag)
               float* __restrict__ out1,       // [TT][BB][2H]
               float* __restrict__ acc,        // [TT][BB]
               const float* __restrict__ fcw,  // [2H]
               int never)
{
    constexpr int KZ   = KIN + HH;
    constexpr int KZP  = KZ + 4;      // W row stride, %32 == 4
    constexpr int KINP = KIN + 4;     // zx row stride, %32 == 4
    constexpr int HHP  = HH + 4;      // zh row stride, %32 == 4
    constexpr int C4   = KIN / 4;
    constexpr int NPX  = (8 * C4) / NTH;   // x-prefetch f32x4/thread (4 / 1)
    constexpr int XIT  = KIN / 32;         // x-part f32x4 iters/thread (16 / 4)
    constexpr int PADN = (LAYER == 1) ? 3072 : 4;  // L1 LDS > 80KB: 1 block/CU

    const int blk  = blockIdx.x;
    const int g    = blk & 7;
    const int rank = blk >> 3;
    const int dir  = g & 1;
    const int bq   = g >> 1;
    const int tid  = threadIdx.x;

    __shared__ __align__(16) float W[32][KZP];
    __shared__ __align__(16) float zx[8][KINP];
    __shared__ __align__(16) float zh[8][HHP];
    __shared__ float red[8][4][8][8];       // [ks][gate][j][b]
    __shared__ float gates_s[4][8][9];
    __shared__ float bias_s[32];
    __shared__ float padlds[PADN];
    if (never) padlds[never & (PADN - 1)] = 1.0f;

    const float* wih = dir ? wih_r : wih_f;
    const float* whh = dir ? whh_r : whh_f;
    const float* bih = dir ? bih_r : bih_f;
    const float* bhh = dir ? bhh_r : bhh_f;

    // ---- one-time: weight slice -> LDS ----
    {
        constexpr int NC = 32 * (KZ / 4);
        for (int q = tid; q < NC; q += NTH) {
            const int r = q / (KZ / 4);
            const int k = (q - r * (KZ / 4)) * 4;
            const int row = (r >> 3) * HH + rank * 8 + (r & 7);
            f32x4 v;
            if (k < KIN) v = *(const f32x4*)(wih + (long)row * KIN + k);
            else         v = *(const f32x4*)(whh + (long)row * HH + (k - KIN));
            *(f32x4*)&W[r][k] = v;
        }
        if (tid < 32) {
            const int row = (tid >> 3) * HH + rank * 8 + (tid & 7);
            bias_s[tid] = bih[row] + bhh[row];
        }
    }

    u32* hbt_g = hbt + g * (2 * 8 * 256 * 2);
    float* hs_seed = hseed + g * (8 * HH);
    float* cs_seed = cseed + g * (8 * HH);

    // dot roles: thread = (ks 8, jD 8, bg 4); rows = 4 gates x jD; b = 2bg,2bg+1
    const int ks = tid >> 5;
    const int jD = (tid >> 2) & 7;
    const int bg = tid & 3;

    // final-sum roles
    const int g2 = tid >> 6;
    const int j2 = (tid >> 3) & 7;
    const int b2 = tid & 7;

    // update roles (tid < 64)
    const int jj2   = tid >> 3;
    const int bl2   = tid & 7;
    const int jglob = rank * 8 + jj2;

    // consumer roles: thread owns 8 consecutive j for one b
    const int bcol = tid >> 5;
    const int jq   = (tid & 31) * 8;

    float creg = 0.0f, fcv = 0.0f;
    if (tid < 64) {
        if (LAYER == 2) { creg = cs_seed[bl2 * HH + jglob]; fcv = fcw[dir * HH + jglob]; }
    }

    // ---- prolog: zx for s=0; seed packets (state 0, tag 1) ----
    {
        const int t0 = dir ? (TT - 1) : 0;
        const long tb = (long)t0 * st;
        for (int q = tid; q < 8 * C4; q += NTH) {
            const int bl = q / C4;
            const int k4 = q - bl * C4;
            *(f32x4*)&zx[bl][k4 * 4] =
                *(const f32x4*)(in_seq + (long)(bq * 8 + bl) * sb + tb + k4 * 4);
        }
        if (tid < 64) {
            const float h0 = (LAYER == 1) ? 0.0f : hs_seed[bl2 * HH + jglob];
            const u32 hx = __float_as_uint(h0);
            u32x2 pkt; pkt.x = hx; pkt.y = 1u + hx * HASHK;
            u32* pp = hbt_g + ((0 * 8 + bl2) * 256 + jglob) * 2;
            asm volatile("global_store_dwordx2 %0, %1, off sc0 sc1"
                         :: "v"(pp), "v"(pkt) : "memory");
        }
    }
    __syncthreads();

    for (int s = 0; s < TT; ++s) {
        const int t = dir ? (TT - 1 - s) : s;

        // ---- P0: prefetch x slice for step s+1 ----
        f32x4 px[NPX];
        if (s + 1 < TT) {
            const long tb = (long)(dir ? (t - 1) : (t + 1)) * st;
            #pragma unroll
            for (int i = 0; i < NPX; ++i) {
                const int q  = tid + i * NTH;
                const int bl = q / C4;
                const int k4 = q - bl * C4;
                px[i] = *(const f32x4*)(in_seq + (long)(bq * 8 + bl) * sb + tb + k4 * 4);
            }
        }

        // ---- P1: x-part partial dots (4 gates x 2 b per thread) ----
        float a00 = 0.f, a01 = 0.f, a10 = 0.f, a11 = 0.f;
        float a20 = 0.f, a21 = 0.f, a30 = 0.f, a31 = 0.f;
        {
            const int kb = ks * (KIN / 8);
            #pragma unroll 4
            for (int k4 = 0; k4 < XIT; ++k4) {
                const int k = kb + k4 * 4;
                const f32x4 z0 = *(const f32x4*)&zx[2 * bg][k];
                const f32x4 z1 = *(const f32x4*)&zx[2 * bg + 1][k];
                #define XDOT(gi, A0, A1) { \
                    const f32x4 w = *(const f32x4*)&W[gi * 8 + jD][k]; \
                    A0 = fmaf(w.x,z0.x,fmaf(w.y,z0.y,fmaf(w.z,z0.z,fmaf(w.w,z0.w,A0)))); \
                    A1 = fmaf(w.x,z1.x,fmaf(w.y,z1.y,fmaf(w.z,z1.z,fmaf(w.w,z1.w,A1)))); }
                XDOT(0, a00, a01) XDOT(1, a10, a11) XDOT(2, a20, a21) XDOT(3, a30, a31)
                #undef XDOT
            }
        }

        // ---- P2: spin-load tagged h packets -> zh ----
        {
            const u32 tg = (u32)(s + 1);
            const u32* hp = hbt_g + (((s & 1) * 8 + bcol) * 256 + jq) * 2;
            u32x4 q0, q1, q2, q3;
            while (true) {
                asm volatile(
                    "global_load_dwordx4 %0, %4, off sc0 sc1\n\t"
                    "global_load_dwordx4 %1, %4, off offset:16 sc0 sc1\n\t"
                    "global_load_dwordx4 %2, %4, off offset:32 sc0 sc1\n\t"
                    "global_load_dwordx4 %3, %4, off offset:48 sc0 sc1\n\t"
                    "s_waitcnt vmcnt(0)"
                    : "=&v"(q0), "=&v"(q1), "=&v"(q2), "=&v"(q3)
                    : "v"(hp) : "memory");
                const bool ok =
                    (q0.y - q0.x * HASHK == tg) && (q0.w - q0.z * HASHK == tg) &&
                    (q1.y - q1.x * HASHK == tg) && (q1.w - q1.z * HASHK == tg) &&
                    (q2.y - q2.x * HASHK == tg) && (q2.w - q2.z * HASHK == tg) &&
                    (q3.y - q3.x * HASHK == tg) && (q3.w - q3.z * HASHK == tg);
                if (ok) break;
                __builtin_amdgcn_s_sleep(1);
            }
            zh[bcol][jq + 0] = __uint_as_float(q0.x);
            zh[bcol][jq + 1] = __uint_as_float(q0.z);
            zh[bcol][jq + 2] = __uint_as_float(q1.x);
            zh[bcol][jq + 3] = __uint_as_float(q1.z);
            zh[bcol][jq + 4] = __uint_as_float(q2.x);
            zh[bcol][jq + 5] = __uint_as_float(q2.z);
            zh[bcol][jq + 6] = __uint_as_float(q3.x);
            zh[bcol][jq + 7] = __uint_as_float(q3.z);
        }
        __syncthreads();

        // ---- P3: h-part partial dots + write partials ----
        {
            const int hb = ks * 32;
            #pragma unroll 4
            for (int k4 = 0; k4 < 8; ++k4) {
                const int k = hb + k4 * 4;
                const f32x4 z0 = *(const f32x4*)&zh[2 * bg][k];
                const f32x4 z1 = *(const f32x4*)&zh[2 * bg + 1][k];
                #define HDOT(gi, A0, A1) { \
                    const f32x4 w = *(const f32x4*)&W[gi * 8 + jD][KIN + k]; \
                    A0 = fmaf(w.x,z0.x,fmaf(w.y,z0.y,fmaf(w.z,z0.z,fmaf(w.w,z0.w,A0)))); \
                    A1 = fmaf(w.x,z1.x,fmaf(w.y,z1.y,fmaf(w.z,z1.z,fmaf(w.w,z1.w,A1)))); }
                HDOT(0, a00, a01) HDOT(1, a10, a11) HDOT(2, a20, a21) HDOT(3, a30, a31)
                #undef HDOT
            }
            red[ks][0][jD][2 * bg] = a00; red[ks][0][jD][2 * bg + 1] = a01;
            red[ks][1][jD][2 * bg] = a10; red[ks][1][jD][2 * bg + 1] = a11;
            red[ks][2][jD][2 * bg] = a20; red[ks][2][jD][2 * bg + 1] = a21;
            red[ks][3][jD][2 * bg] = a30; red[ks][3][jD][2 * bg + 1] = a31;
        }
        __syncthreads();

        // ---- P4: reduce k-slices -> gate pre-activations ----
        {
            float sg = bias_s[g2 * 8 + j2];
            #pragma unroll
            for (int q = 0; q < 8; ++q) sg += red[q][g2][j2][b2];
            gates_s[g2][j2][b2] = sg;
        }
        __syncthreads();

        // ---- P5: cell update, tagged h store, outputs; stage px -> zx ----
        if (tid < 64) {
            const float gi = gates_s[0][jj2][bl2];
            const float gf = gates_s[1][jj2][bl2];
            const float gg = gates_s[2][jj2][bl2];
            const float go = gates_s[3][jj2][bl2];
            creg = sigm(gf) * creg + sigm(gi) * tanh_f(gg);
            const float hv = sigm(go) * tanh_f(creg);
            if (s + 1 < TT) {
                const u32 hx = __float_as_uint(hv);
                u32x2 pkt; pkt.x = hx; pkt.y = (u32)(s + 2) + hx * HASHK;
                u32* pp = hbt_g + ((((s + 1) & 1) * 8 + bl2) * 256 + jglob) * 2;
                asm volatile("global_store_dwordx2 %0, %1, off sc0 sc1"
                             :: "v"(pp), "v"(pkt) : "memory");
            }
            if (LAYER == 1) {
                out1[(long)t * (BB * 2 * HH) + (bq * 8 + bl2) * (2 * HH) + dir * HH + jglob] = hv;
                if (s == TT - 1) {
                    hs_seed[bl2 * HH + jglob] = hv;
                    cs_seed[bl2 * HH + jglob] = creg;
                }
            } else {
                float val = hv * fcv;
                val += __shfl_down(val, 32, 64);
                val += __shfl_down(val, 16, 64);
                val += __shfl_down(val, 8, 64);
                if (jj2 == 0) atomicAdd(&acc[t * BB + bq * 8 + bl2], val);
            }
        }
        if (s + 1 < TT) {
            #pragma unroll
            for (int i = 0; i < NPX; ++i) {
                const int q  = tid + i * NTH;
                const int bl = q / C4;
                const int k4 = q - bl * C4;
                *(f32x4*)&zx[bl][k4 * 4] = px[i];
            }
        }
        __syncthreads();
    }
}

__global__ void finalize_k(const float* __restrict__ acc, const float* __restrict__ fcb,
                           float* __restrict__ out)
{
    const int i = blockIdx.x * blockDim.x + threadIdx.x;
    if (i < BB * TT) {
        const int b = i >> 11;
        const int t = i & (TT - 1);
        out[i] = tanhf(acc[t * BB + b] + fcb[0]);
    }
}

extern "C" void kernel_launch(void* const* d_in, const int* in_sizes, int n_in,
                              void* d_out, int out_size, void* d_ws, size_t ws_size,
                              hipStream_t stream) {
    const float* x     = (const float*)d_in[0];
    const float* wih1f = (const float*)d_in[1];
    const float* whh1f = (const float*)d_in[2];
    const float* bih1f = (const float*)d_in[3];
    const float* bhh1f = (const float*)d_in[4];
    const float* wih1r = (const float*)d_in[5];
    const float* whh1r = (const float*)d_in[6];
    const float* bih1r = (const float*)d_in[7];
    const float* bhh1r = (const float*)d_in[8];
    const float* wih2f = (const float*)d_in[9];
    const float* whh2f = (const float*)d_in[10];
    const float* bih2f = (const float*)d_in[11];
    const float* bhh2f = (const float*)d_in[12];
    const float* wih2r = (const float*)d_in[13];
    const float* whh2r = (const float*)d_in[14];
    const float* bih2r = (const float*)d_in[15];
    const float* bhh2r = (const float*)d_in[16];
    const float* fcw   = (const float*)d_in[17];
    const float* fcb   = (const float*)d_in[18];

    char* ws = (char*)d_ws;
    size_t off = 0;
    float* acc  = (float*)(ws + off); off += (size_t)TT * BB * 4;                // 256 KB
    u32* hbt1   = (u32*)(ws + off);   off += (size_t)NGRP * 2 * 8 * 256 * 2 * 4; // 256 KB
    u32* hbt2   = (u32*)(ws + off);   off += (size_t)NGRP * 2 * 8 * 256 * 2 * 4; // 256 KB
    float* hseed = (float*)(ws + off); off += (size_t)NGRP * 8 * HH * 4;         // 64 KB
    float* cseed = (float*)(ws + off); off += (size_t)NGRP * 8 * HH * 4;         // 64 KB
    const size_t clear_bytes = off;
    float* out1 = (float*)(ws + off); off += (size_t)TT * BB * 2 * HH * 4;       // 128 MB

    // acc (atomic target), packet buffers (tag space), seeds: zero each launch
    hipMemsetAsync(d_ws, 0, clear_bytes, stream);

    // layer 1: x (B,T,D)
    lstm_scan<DD, 1><<<NGRP * NRANK, NTH, 0, stream>>>(
        x, (long)TT * DD, (long)DD,
        wih1f, whh1f, bih1f, bhh1f, wih1r, whh1r, bih1r, bhh1r,
        hseed, cseed, hbt1, out1, nullptr, nullptr, 0);

    // layer 2: out1 (T,B,2H); seeds = layer-1 finals
    lstm_scan<2 * HH, 2><<<NGRP * NRANK, NTH, 0, stream>>>(
        out1, (long)(2 * HH), (long)(BB * 2 * HH),
        wih2f, whh2f, bih2f, bhh2f, wih2r, whh2r, bih2r, bhh2r,
        hseed, cseed, hbt2, nullptr, acc, fcw, 0);

    finalize_k<<<(BB * TT + 255) / 256, 256, 0, stream>>>(acc, fcb, (float*)d_out);
}

// Round 5
// 12804.005 us; speedup vs baseline: 7.9267x; 1.0455x over previous
//
#include <hip/hip_runtime.h>

#define BB 32      // batch
#define TT 2048    // time steps
#define DD 128     // input dim (layer 1)
#define HH 256     // hidden
#define NTH 256    // threads per block
#define NRANK 32   // blocks (ranks) per group
#define NGRP 8     // groups = 2 dirs x 4 batch-quads
#define HASHK 2654435761u

typedef float f32x4 __attribute__((ext_vector_type(4)));
typedef unsigned int u32;
typedef u32 u32x2 __attribute__((ext_vector_type(2)));
typedef u32 u32x4 __attribute__((ext_vector_type(4)));

__device__ __forceinline__ float sigm(float x)  { return 1.0f / (1.0f + __expf(-x)); }
__device__ __forceinline__ float tanh_f(float x){ return 1.0f - 2.0f / (__expf(2.0f * x) + 1.0f); }

// Persistent bidirectional scan; 256 blocks = 8 groups x 32 ranks, 1 block/CU.
// W lives in REGISTERS (96 VGPR/thread L2, 48 L1) -- zero LDS traffic for W.
// Thread (rg 0..7, sl 0..31): rows rg*4..rg*4+3, k-slice {sl*4+128c}.
// h exchange: (h, tag) packets (tag = step + h_bits*HASHK) via IC sc0 sc1,
// j-major layout for coalesced producer stores + conflict-free unpack.
template<int KIN, int LAYER>
__global__ __launch_bounds__(NTH, 1)
void lstm_scan(const float* __restrict__ in_seq, long sb, long st,
               const float* __restrict__ wih_f, const float* __restrict__ whh_f,
               const float* __restrict__ bih_f, const float* __restrict__ bhh_f,
               const float* __restrict__ wih_r, const float* __restrict__ whh_r,
               const float* __restrict__ bih_r, const float* __restrict__ bhh_r,
               float* __restrict__ hseed,      // [NGRP][8][HH]
               float* __restrict__ cseed,      // [NGRP][8][HH]
               u32* __restrict__ hbt,          // [NGRP][2par][256j][8b][2]
               float* __restrict__ out1,       // [TT][BB][2H]
               float* __restrict__ acc,        // [TT][BB]
               const float* __restrict__ fcw,  // [2H]
               int never)
{
    constexpr int KZ   = KIN + HH;
    constexpr int KINP = KIN + 4;   // zx stride: odd # of 16B slots -> %8 spread
    constexpr int HHP  = HH + 4;    // zh stride: 65 slots, odd
    constexpr int C4   = KIN / 4;
    constexpr int XC   = KIN / 128;             // x chunks/thread (1 / 4)
    constexpr int NPX  = (8 * C4) / NTH;        // x-prefetch f32x4/thread (1 / 4)
    constexpr int RSTR = 36;                    // red2 stride (floats), 9 slots
    constexpr int PADN = (LAYER == 1) ? 8192 : 5120;  // force LDS > 80KB: 1 blk/CU

    const int blk  = blockIdx.x;
    const int g    = blk & 7;
    const int rank = blk >> 3;
    const int dir  = g & 1;
    const int bq   = g >> 1;
    const int tid  = threadIdx.x;

    __shared__ __align__(16) float zx[8][KINP];
    __shared__ __align__(16) float zh[8][HHP];
    __shared__ __align__(16) float red2[256 * RSTR];
    __shared__ float gates_s[4][8][9];
    __shared__ float bias_s[32];
    __shared__ float padlds[PADN];
    if (never) padlds[never & (PADN - 1)] = 1.0f;

    const float* wih = dir ? wih_r : wih_f;
    const float* whh = dir ? whh_r : whh_f;
    const float* bih = dir ? bih_r : bih_f;
    const float* bhh = dir ? bhh_r : bhh_f;

    // dot roles
    const int rg = tid >> 5;        // row group: rows rg*4 .. rg*4+3
    const int sl = tid & 31;        // k-slice

    // ---- one-time: W slice -> REGISTERS ----
    f32x4 wx[4][XC], wh[4][2];
    #pragma unroll
    for (int rr = 0; rr < 4; ++rr) {
        const int r = rg * 4 + rr;                       // 0..31
        const int grow = (r >> 3) * HH + rank * 8 + (r & 7);
        #pragma unroll
        for (int c = 0; c < XC; ++c)
            wx[rr][c] = *(const f32x4*)(wih + (long)grow * KIN + sl * 4 + 128 * c);
        #pragma unroll
        for (int c = 0; c < 2; ++c)
            wh[rr][c] = *(const f32x4*)(whh + (long)grow * HH + sl * 4 + 128 * c);
    }
    if (tid < 32) {
        const int grow = (tid >> 3) * HH + rank * 8 + (tid & 7);
        bias_s[tid] = bih[grow] + bhh[grow];
    }

    u32* hbt_g = hbt + g * (2 * 256 * 8 * 2);
    float* hs_seed = hseed + g * (8 * HH);
    float* cs_seed = cseed + g * (8 * HH);

    // update roles (tid < 64)
    const int jj2   = tid >> 3;
    const int bl2   = tid & 7;
    const int jglob = rank * 8 + jj2;

    float creg = 0.0f, fcv = 0.0f;
    if (tid < 64 && LAYER == 2) {
        creg = cs_seed[bl2 * HH + jglob];
        fcv  = fcw[dir * HH + jglob];
    }

    // ---- prolog: zx for s=0; seed packets (tag 1) ----
    {
        const int t0 = dir ? (TT - 1) : 0;
        const long tb = (long)t0 * st;
        for (int q = tid; q < 8 * C4; q += NTH) {
            const int bl = q / C4;
            const int k4 = q - bl * C4;
            *(f32x4*)&zx[bl][k4 * 4] =
                *(const f32x4*)(in_seq + (long)(bq * 8 + bl) * sb + tb + k4 * 4);
        }
        if (tid < 64) {
            const float h0 = (LAYER == 1) ? 0.0f : hs_seed[bl2 * HH + jglob];
            const u32 hx = __float_as_uint(h0);
            u32x2 pkt; pkt.x = hx; pkt.y = 1u + hx * HASHK;
            u32* pp = hbt_g + ((0 * 256 + jglob) * 8 + bl2) * 2;
            asm volatile("global_store_dwordx2 %0, %1, off sc0 sc1"
                         :: "v"(pp), "v"(pkt) : "memory");
        }
    }
    __syncthreads();

    for (int s = 0; s < TT; ++s) {
        const int t = dir ? (TT - 1 - s) : s;

        // ---- P0: prefetch x slice for step s+1 ----
        f32x4 px[NPX];
        if (s + 1 < TT) {
            const long tb = (long)(dir ? (t - 1) : (t + 1)) * st;
            #pragma unroll
            for (int i = 0; i < NPX; ++i) {
                const int q  = tid + i * NTH;
                const int bl = q / C4;
                const int k4 = q - bl * C4;
                px[i] = *(const f32x4*)(in_seq + (long)(bq * 8 + bl) * sb + tb + k4 * 4);
            }
        }

        // ---- P1: x-part of dot (W in regs, z from LDS) ----
        float ac[4][8];
        #pragma unroll
        for (int rr = 0; rr < 4; ++rr)
            #pragma unroll
            for (int b = 0; b < 8; ++b) ac[rr][b] = 0.0f;
        #pragma unroll
        for (int c = 0; c < XC; ++c) {
            f32x4 zv[8];
            #pragma unroll
            for (int b = 0; b < 8; ++b)
                zv[b] = *(const f32x4*)&zx[b][sl * 4 + 128 * c];
            #pragma unroll
            for (int rr = 0; rr < 4; ++rr) {
                const f32x4 w = wx[rr][c];
                #pragma unroll
                for (int b = 0; b < 8; ++b)
                    ac[rr][b] = fmaf(w.x, zv[b].x, fmaf(w.y, zv[b].y,
                                fmaf(w.z, zv[b].z, fmaf(w.w, zv[b].w, ac[rr][b]))));
            }
        }

        // ---- P2: spin-load tagged h packets (thread owns j = tid) ----
        {
            const u32 tg = (u32)(s + 1);
            const u32* hp = hbt_g + (((s & 1) * 256 + tid) * 8) * 2;
            u32x4 q0, q1, q2, q3;
            while (true) {
                asm volatile(
                    "global_load_dwordx4 %0, %4, off sc0 sc1\n\t"
                    "global_load_dwordx4 %1, %4, off offset:16 sc0 sc1\n\t"
                    "global_load_dwordx4 %2, %4, off offset:32 sc0 sc1\n\t"
                    "global_load_dwordx4 %3, %4, off offset:48 sc0 sc1\n\t"
                    "s_waitcnt vmcnt(0)"
                    : "=&v"(q0), "=&v"(q1), "=&v"(q2), "=&v"(q3)
                    : "v"(hp) : "memory");
                const bool ok =
                    (q0.y - q0.x * HASHK == tg) && (q0.w - q0.z * HASHK == tg) &&
                    (q1.y - q1.x * HASHK == tg) && (q1.w - q1.z * HASHK == tg) &&
                    (q2.y - q2.x * HASHK == tg) && (q2.w - q2.z * HASHK == tg) &&
                    (q3.y - q3.x * HASHK == tg) && (q3.w - q3.z * HASHK == tg);
                if (ok) break;
                __builtin_amdgcn_s_sleep(1);
            }
            zh[0][tid] = __uint_as_float(q0.x);
            zh[1][tid] = __uint_as_float(q0.z);
            zh[2][tid] = __uint_as_float(q1.x);
            zh[3][tid] = __uint_as_float(q1.z);
            zh[4][tid] = __uint_as_float(q2.x);
            zh[5][tid] = __uint_as_float(q2.z);
            zh[6][tid] = __uint_as_float(q3.x);
            zh[7][tid] = __uint_as_float(q3.z);
        }
        __syncthreads();

        // ---- P3: h-part of dot + red2 partial writes ----
        #pragma unroll
        for (int c = 0; c < 2; ++c) {
            f32x4 zv[8];
            #pragma unroll
            for (int b = 0; b < 8; ++b)
                zv[b] = *(const f32x4*)&zh[b][sl * 4 + 128 * c];
            #pragma unroll
            for (int rr = 0; rr < 4; ++rr) {
                const f32x4 w = wh[rr][c];
                #pragma unroll
                for (int b = 0; b < 8; ++b)
                    ac[rr][b] = fmaf(w.x, zv[b].x, fmaf(w.y, zv[b].y,
                                fmaf(w.z, zv[b].z, fmaf(w.w, zv[b].w, ac[rr][b]))));
            }
        }
        #pragma unroll
        for (int rr = 0; rr < 4; ++rr)
            #pragma unroll
            for (int b = 0; b < 8; ++b)
                red2[((rg * 4 + rr) * 8 + b) * RSTR + sl] = ac[rr][b];
        __syncthreads();

        // ---- P4: reduce 32 k-slices -> gate pre-activations ----
        {
            float sg = bias_s[tid >> 3];
            const f32x4* rp = (const f32x4*)&red2[tid * RSTR];
            #pragma unroll
            for (int q = 0; q < 8; ++q) {
                const f32x4 v = rp[q];
                sg += v.x + v.y + v.z + v.w;
            }
            gates_s[tid >> 6][(tid >> 3) & 7][tid & 7] = sg;
        }
        __syncthreads();

        // ---- P5: cell update, packet store, outputs; stage px -> zx ----
        if (tid < 64) {
            const float gi = gates_s[0][jj2][bl2];
            const float gf = gates_s[1][jj2][bl2];
            const float gg = gates_s[2][jj2][bl2];
            const float go = gates_s[3][jj2][bl2];
            creg = sigm(gf) * creg + sigm(gi) * tanh_f(gg);
            const float hv = sigm(go) * tanh_f(creg);
            if (s + 1 < TT) {
                const u32 hx = __float_as_uint(hv);
                u32x2 pkt; pkt.x = hx; pkt.y = (u32)(s + 2) + hx * HASHK;
                u32* pp = hbt_g + ((((s + 1) & 1) * 256 + jglob) * 8 + bl2) * 2;
                asm volatile("global_store_dwordx2 %0, %1, off sc0 sc1"
                             :: "v"(pp), "v"(pkt) : "memory");
            }
            if (LAYER == 1) {
                out1[(long)t * (BB * 2 * HH) + (bq * 8 + bl2) * (2 * HH) + dir * HH + jglob] = hv;
                if (s == TT - 1) {
                    hs_seed[bl2 * HH + jglob] = hv;
                    cs_seed[bl2 * HH + jglob] = creg;
                }
            } else {
                float val = hv * fcv;
                val += __shfl_down(val, 32, 64);
                val += __shfl_down(val, 16, 64);
                val += __shfl_down(val, 8, 64);
                if (jj2 == 0) atomicAdd(&acc[t * BB + bq * 8 + bl2], val);
            }
        }
        if (s + 1 < TT) {
            #pragma unroll
            for (int i = 0; i < NPX; ++i) {
                const int q  = tid + i * NTH;
                const int bl = q / C4;
                const int k4 = q - bl * C4;
                *(f32x4*)&zx[bl][k4 * 4] = px[i];
            }
        }
        __syncthreads();
    }
}

__global__ void finalize_k(const float* __restrict__ acc, const float* __restrict__ fcb,
                           float* __restrict__ out)
{
    const int i = blockIdx.x * blockDim.x + threadIdx.x;
    if (i < BB * TT) {
        const int b = i >> 11;
        const int t = i & (TT - 1);
        out[i] = tanhf(acc[t * BB + b] + fcb[0]);
    }
}

extern "C" void kernel_launch(void* const* d_in, const int* in_sizes, int n_in,
                              void* d_out, int out_size, void* d_ws, size_t ws_size,
                              hipStream_t stream) {
    const float* x     = (const float*)d_in[0];
    const float* wih1f = (const float*)d_in[1];
    const float* whh1f = (const float*)d_in[2];
    const float* bih1f = (const float*)d_in[3];
    const float* bhh1f = (const float*)d_in[4];
    const float* wih1r = (const float*)d_in[5];
    const float* whh1r = (const float*)d_in[6];
    const float* bih1r = (const float*)d_in[7];
    const float* bhh1r = (const float*)d_in[8];
    const float* wih2f = (const float*)d_in[9];
    const float* whh2f = (const float*)d_in[10];
    const float* bih2f = (const float*)d_in[11];
    const float* bhh2f = (const float*)d_in[12];
    const float* wih2r = (const float*)d_in[13];
    const float* whh2r = (const float*)d_in[14];
    const float* bih2r = (const float*)d_in[15];
    const float* bhh2r = (const float*)d_in[16];
    const float* fcw   = (const float*)d_in[17];
    const float* fcb   = (const float*)d_in[18];

    char* ws = (char*)d_ws;
    size_t off = 0;
    float* acc  = (float*)(ws + off); off += (size_t)TT * BB * 4;                // 256 KB
    u32* hbt1   = (u32*)(ws + off);   off += (size_t)NGRP * 2 * 256 * 8 * 2 * 4; // 256 KB
    u32* hbt2   = (u32*)(ws + off);   off += (size_t)NGRP * 2 * 256 * 8 * 2 * 4; // 256 KB
    float* hseed = (float*)(ws + off); off += (size_t)NGRP * 8 * HH * 4;         // 64 KB
    float* cseed = (float*)(ws + off); off += (size_t)NGRP * 8 * HH * 4;         // 64 KB
    const size_t clear_bytes = off;
    float* out1 = (float*)(ws + off); off += (size_t)TT * BB * 2 * HH * 4;       // 128 MB

    // acc (atomic target), packet buffers (tag space), seeds: zero each launch
    hipMemsetAsync(d_ws, 0, clear_bytes, stream);

    // layer 1: x (B,T,D)
    lstm_scan<DD, 1><<<NGRP * NRANK, NTH, 0, stream>>>(
        x, (long)TT * DD, (long)DD,
        wih1f, whh1f, bih1f, bhh1f, wih1r, whh1r, bih1r, bhh1r,
        hseed, cseed, hbt1, out1, nullptr, nullptr, 0);

    // layer 2: out1 (T,B,2H); seeds = layer-1 finals
    lstm_scan<2 * HH, 2><<<NGRP * NRANK, NTH, 0, stream>>>(
        out1, (long)(2 * HH), (long)(BB * 2 * HH),
        wih2f, whh2f, bih2f, bhh2f, wih2r, whh2r, bih2r, bhh2r,
        hseed, cseed, hbt2, nullptr, acc, fcw, 0);

    finalize_k<<<(BB * TT + 255) / 256, 256, 0, stream>>>(acc, fcb, (float*)d_out);
}